// Round 2
// baseline (1944.964 us; speedup 1.0000x reference)
//
#include <hip/hip_runtime.h>

#define NPTS 8192
#define NB 4
#define CH 64
#define KNN 16

__device__ __forceinline__ float bf2f(unsigned short u) {
    return __uint_as_float(((unsigned)u) << 16);
}
__device__ __forceinline__ unsigned short f2bf(float f) {
    unsigned u = __float_as_uint(f);
    u += 0x7fffu + ((u >> 16) & 1u);   // round-to-nearest-even
    return (unsigned short)(u >> 16);
}

template <bool F32>
__device__ __forceinline__ float LD(const void* p, long i) {
    if (F32) return ((const float*)p)[i];
    return bf2f(((const unsigned short*)p)[i]);
}

// ---------------- Kernel 0: dtype detector ----------------
// f32 data read as bf16 ushorts -> low mantissa halves decode to huge magnitudes.
__global__ void detect_kernel(const unsigned short* __restrict__ pts, int* __restrict__ flag) {
    if (threadIdx.x == 0 && blockIdx.x == 0) {
        int huge = 0;
        for (int i = 0; i < 512; ++i) {
            const float f = fabsf(bf2f(pts[i]));
            if (f > 1e10f) ++huge;
        }
        *flag = (huge >= 4) ? 1 : 0;   // 1 = float32 inputs, 0 = bf16 inputs
    }
}

// ---------------- Kernel 1: brute-force KNN (top-16, stable tie-break) ----------------
template <bool F32>
__global__ __launch_bounds__(128) void knn_kernel(const void* __restrict__ pts,
                                                  int* __restrict__ ws) {
    if (ws[0] != (F32 ? 1 : 0)) return;          // uniform dtype gate
    int* idx_out = ws + 256;                     // knn indices @ +1KB

    __shared__ float4 tile[128];
    const int q = blockIdx.x * 128 + threadIdx.x;   // 0..32767
    const int b = q >> 13;
    const int n = q & (NPTS - 1);
    const long pb = (long)b * NPTS * 3;

    const float px = LD<F32>(pts, pb + n * 3 + 0);
    const float py = LD<F32>(pts, pb + n * 3 + 1);
    const float pz = LD<F32>(pts, pb + n * 3 + 2);
    const float sqi = (px * px + py * py) + pz * pz;

    float dist[KNN];
    int   idx[KNN];
#pragma unroll
    for (int m = 0; m < KNN; ++m) { dist[m] = 3.4e38f; idx[m] = 0; }

    for (int t = 0; t < NPTS / 128; ++t) {
        const int j0 = t * 128;
        {
            const int c = j0 + threadIdx.x;
            const float x = LD<F32>(pts, pb + c * 3 + 0);
            const float y = LD<F32>(pts, pb + c * 3 + 1);
            const float z = LD<F32>(pts, pb + c * 3 + 2);
            const float s = (x * x + y * y) + z * z;
            tile[threadIdx.x] = make_float4(x, y, z, s);
        }
        __syncthreads();
#pragma unroll 4
        for (int jj = 0; jj < 128; ++jj) {
            const float4 v = tile[jj];
            float dot = px * v.x;
            dot = fmaf(py, v.y, dot);
            dot = fmaf(pz, v.z, dot);
            // d = (sq_i + sq_j) - 2*dot ; 2*dot exact so fma == separate rounding
            const float d = fmaf(dot, -2.0f, sqi + v.w);
            if (d < dist[KNN - 1]) {
                float cd = d;
                int   ci = j0 + jj;
#pragma unroll
                for (int m = 0; m < KNN; ++m) {
                    const bool sw = cd < dist[m];   // strict < : lower-index-first on ties
                    const float td = sw ? dist[m] : cd;
                    const int   ti = sw ? idx[m] : ci;
                    dist[m] = sw ? cd : dist[m];
                    idx[m]  = sw ? ci : idx[m];
                    cd = td; ci = ti;
                }
            }
        }
        __syncthreads();
    }
    int* op = idx_out + (size_t)q * KNN;
#pragma unroll
    for (int m = 0; m < KNN; ++m) op[m] = idx[m];
}

// ---------------- Kernel 2: gather + 3 MLPs + max over k ----------------
// one block (256 threads) handles 16 points; weights staged (as bf16) in LDS once.
template <bool F32>
__global__ __launch_bounds__(256) void agg_kernel(
    const void* __restrict__ pts,
    const void* __restrict__ feat,
    const void* __restrict__ w_geom,
    const void* __restrict__ g1, const void* __restrict__ b1,
    const void* __restrict__ m1, const void* __restrict__ v1,
    const void* __restrict__ w_sem,
    const void* __restrict__ g2, const void* __restrict__ b2,
    const void* __restrict__ m2, const void* __restrict__ v2,
    const void* __restrict__ w_fuse,
    const void* __restrict__ g3, const void* __restrict__ b3,
    const void* __restrict__ m3, const void* __restrict__ v3,
    int* __restrict__ ws,
    void* __restrict__ outp) {

    if (ws[0] != (F32 ? 1 : 0)) return;          // uniform dtype gate
    const int* knn_idx = ws + 256;

    // weights as bf16 quads: [c/4][o][4] -> lane-o b64 reads
    __shared__ alignas(16) unsigned short s_wsem[32][64][4];
    __shared__ alignas(16) unsigned short s_wfuse[32][64][4];
    __shared__ float s_wgeomT[6][64];
    __shared__ float s_s1[64], s_b1[64], s_s2[64], s_b2[64], s_s3[64], s_b3[64];
    __shared__ alignas(16) float s_ctrf[64];
    __shared__ float s_ctrp[4];
    __shared__ int   s_nidx[16];
    __shared__ float s_gdel[16][4];
    __shared__ alignas(16) float s_sdelta[16][64];
    __shared__ alignas(16) float s_mid[16][128];
    __shared__ float s_pmax[4][64];

    const int tid = threadIdx.x;

    for (int e = tid; e < 64 * 128; e += 256) {
        const int o = e >> 7, c = e & 127;
        const unsigned short ws16 = F32 ? f2bf(((const float*)w_sem)[e])
                                        : ((const unsigned short*)w_sem)[e];
        const unsigned short wf16 = F32 ? f2bf(((const float*)w_fuse)[e])
                                        : ((const unsigned short*)w_fuse)[e];
        s_wsem [c >> 2][o][c & 3] = ws16;
        s_wfuse[c >> 2][o][c & 3] = wf16;
    }
    for (int e = tid; e < 64 * 6; e += 256) {
        const int o = e / 6, c = e - o * 6;
        s_wgeomT[c][o] = LD<F32>(w_geom, e);
    }
    if (tid < 64) {
        float s;
        s = LD<F32>(g1, tid) / sqrtf(LD<F32>(v1, tid) + 1e-5f);
        s_s1[tid] = s; s_b1[tid] = LD<F32>(b1, tid) - LD<F32>(m1, tid) * s;
        s = LD<F32>(g2, tid) / sqrtf(LD<F32>(v2, tid) + 1e-5f);
        s_s2[tid] = s; s_b2[tid] = LD<F32>(b2, tid) - LD<F32>(m2, tid) * s;
        s = LD<F32>(g3, tid) / sqrtf(LD<F32>(v3, tid) + 1e-5f);
        s_s3[tid] = s; s_b3[tid] = LD<F32>(b3, tid) - LD<F32>(m3, tid) * s;
    }
    __syncthreads();

    const int o = tid & 63, kg = tid >> 6;

    for (int p = 0; p < 16; ++p) {
        const int pv = blockIdx.x * 16 + p;       // 0..32767
        const int b = pv >> 13, n = pv & (NPTS - 1);
        const long pbase = (long)b * NPTS + n;

        if (tid < 16) s_nidx[tid] = knn_idx[pbase * KNN + tid];
        if (tid < 64) s_ctrf[tid] = LD<F32>(feat, pbase * CH + tid);
        if (tid < 3)  s_ctrp[tid] = LD<F32>(pts, pbase * 3 + tid);
        __syncthreads();

#pragma unroll
        for (int ki = 0; ki < 4; ++ki) {
            const int k = kg * 4 + ki;
            const long nb = (long)b * NPTS + s_nidx[k];
            s_sdelta[k][o] = LD<F32>(feat, nb * CH + o) - s_ctrf[o];
        }
        if (tid < 16) {
            const long nb = (long)b * NPTS + s_nidx[tid];
            s_gdel[tid][0] = LD<F32>(pts, nb * 3 + 0) - s_ctrp[0];
            s_gdel[tid][1] = LD<F32>(pts, nb * 3 + 1) - s_ctrp[1];
            s_gdel[tid][2] = LD<F32>(pts, nb * 3 + 2) - s_ctrp[2];
        }
        __syncthreads();

        // k-invariant center contributions (reused over all 16 k)
        float accc = 0.f;
#pragma unroll
        for (int qd = 0; qd < 16; ++qd) {
            const ushort4 w = *(const ushort4*)&s_wsem[qd][o][0];
            const float4 cv = *(const float4*)&s_ctrf[qd * 4];
            accc = fmaf(cv.x, bf2f(w.x), accc);
            accc = fmaf(cv.y, bf2f(w.y), accc);
            accc = fmaf(cv.z, bf2f(w.z), accc);
            accc = fmaf(cv.w, bf2f(w.w), accc);
        }
        float cg = s_ctrp[0] * s_wgeomT[0][o];
        cg = fmaf(s_ctrp[1], s_wgeomT[1][o], cg);
        cg = fmaf(s_ctrp[2], s_wgeomT[2][o], cg);

        const float s1o = s_s1[o], b1o = s_b1[o];
        const float s2o = s_s2[o], b2o = s_b2[o];

#pragma unroll
        for (int ki = 0; ki < 4; ++ki) {
            const int k = kg * 4 + ki;
            float g = cg;
            g = fmaf(s_gdel[k][0], s_wgeomT[3][o], g);
            g = fmaf(s_gdel[k][1], s_wgeomT[4][o], g);
            g = fmaf(s_gdel[k][2], s_wgeomT[5][o], g);
            const float gf = fmaxf(fmaf(g, s1o, b1o), 0.f);

            float a = accc;
#pragma unroll
            for (int qd = 0; qd < 16; ++qd) {
                const ushort4 w = *(const ushort4*)&s_wsem[16 + qd][o][0];
                const float4 dv = *(const float4*)&s_sdelta[k][qd * 4];
                a = fmaf(dv.x, bf2f(w.x), a);
                a = fmaf(dv.y, bf2f(w.y), a);
                a = fmaf(dv.z, bf2f(w.z), a);
                a = fmaf(dv.w, bf2f(w.w), a);
            }
            const float sf = fmaxf(fmaf(a, s2o, b2o), 0.f);
            s_mid[k][o] = gf;
            s_mid[k][64 + o] = sf;
        }
        __syncthreads();

        const float s3o = s_s3[o], b3o = s_b3[o];
        float fmx = 0.f;   // relu outputs are >= 0
#pragma unroll
        for (int ki = 0; ki < 4; ++ki) {
            const int k = kg * 4 + ki;
            float a = 0.f;
#pragma unroll
            for (int qd = 0; qd < 32; ++qd) {
                const ushort4 w = *(const ushort4*)&s_wfuse[qd][o][0];
                const float4 mv = *(const float4*)&s_mid[k][qd * 4];
                a = fmaf(mv.x, bf2f(w.x), a);
                a = fmaf(mv.y, bf2f(w.y), a);
                a = fmaf(mv.z, bf2f(w.z), a);
                a = fmaf(mv.w, bf2f(w.w), a);
            }
            const float fu = fmaxf(fmaf(a, s3o, b3o), 0.f);
            fmx = fmaxf(fmx, fu);
        }
        s_pmax[kg][o] = fmx;
        __syncthreads();

        if (tid < 64) {
            const float r = fmaxf(fmaxf(s_pmax[0][tid], s_pmax[1][tid]),
                                  fmaxf(s_pmax[2][tid], s_pmax[3][tid]));
            if (F32) ((float*)outp)[pbase * CH + tid] = r;
            else     ((unsigned short*)outp)[pbase * CH + tid] = f2bf(r);
        }
        __syncthreads();
    }
}

extern "C" void kernel_launch(void* const* d_in, const int* in_sizes, int n_in,
                              void* d_out, int out_size, void* d_ws, size_t ws_size,
                              hipStream_t stream) {
    (void)in_sizes; (void)n_in; (void)out_size; (void)ws_size;
    const void* pts    = d_in[0];
    const void* feat   = d_in[1];
    const void* w_geom = d_in[2];
    const void* g1     = d_in[3];
    const void* b1     = d_in[4];
    const void* m1     = d_in[5];
    const void* v1     = d_in[6];
    const void* w_sem  = d_in[7];
    const void* g2     = d_in[8];
    const void* b2     = d_in[9];
    const void* m2     = d_in[10];
    const void* v2     = d_in[11];
    const void* w_fuse = d_in[12];
    const void* g3     = d_in[13];
    const void* b3     = d_in[14];
    const void* m3     = d_in[15];
    const void* v3     = d_in[16];

    int* ws = (int*)d_ws;   // ws[0]=dtype flag; knn idx @ ws+256 (2MB)

    detect_kernel<<<1, 64, 0, stream>>>((const unsigned short*)pts, ws);
    knn_kernel<false><<<dim3(256), dim3(128), 0, stream>>>(pts, ws);
    knn_kernel<true ><<<dim3(256), dim3(128), 0, stream>>>(pts, ws);
    agg_kernel<false><<<dim3(2048), dim3(256), 0, stream>>>(
        pts, feat, w_geom, g1, b1, m1, v1, w_sem, g2, b2, m2, v2,
        w_fuse, g3, b3, m3, v3, ws, d_out);
    agg_kernel<true ><<<dim3(2048), dim3(256), 0, stream>>>(
        pts, feat, w_geom, g1, b1, m1, v1, w_sem, g2, b2, m2, v2,
        w_fuse, g3, b3, m3, v3, ws, d_out);
}